// Round 1
// baseline (439.095 us; speedup 1.0000x reference)
//
#include <hip/hip_runtime.h>
#include <math.h>

#define D_IN   4096
#define D_OUT  4096
#define M_ROWS 8192          // B*S = 4*2048
#define RANK   8
#define SCALING 2.0f
#define EPS_N  1e-8f

// ---------------------------------------------------------------------------
// Pass 1: per-output-row norm of updated weight -> mag_scale[o], and the
// pre-folded epilogue table Bm[o][r] = SCALING * lora_B[o][r] * mag_scale[o].
// Block = 4 waves; wave w handles row o = blockIdx.x*4 + w.
// A (128 KB) is shared across all rows -> L1/L2 resident.
// ---------------------------------------------------------------------------
__global__ __launch_bounds__(256) void k_magscale(
    const float* __restrict__ W,     // [D_OUT, D_IN]
    const float* __restrict__ A,     // [RANK, D_IN]
    const float* __restrict__ Bl,    // [D_OUT, RANK]
    const float* __restrict__ mag,   // [D_OUT]
    float* __restrict__ mag_scale,   // [D_OUT]
    float* __restrict__ Bm)          // [D_OUT, RANK]
{
    const int wave = threadIdx.x >> 6;
    const int lane = threadIdx.x & 63;
    const int o = blockIdx.x * 4 + wave;
    const float* Wrow = W + (size_t)o * D_IN;

    float b[RANK];
#pragma unroll
    for (int r = 0; r < RANK; ++r) b[r] = Bl[o * RANK + r];

    float acc = 0.f;
    for (int i = lane * 4; i < D_IN; i += 64 * 4) {
        float4 w4 = *(const float4*)(Wrow + i);
        float dx = 0.f, dy = 0.f, dz = 0.f, dw = 0.f;
#pragma unroll
        for (int r = 0; r < RANK; ++r) {
            float4 a4 = *(const float4*)(A + r * D_IN + i);
            dx += b[r] * a4.x; dy += b[r] * a4.y;
            dz += b[r] * a4.z; dw += b[r] * a4.w;
        }
        float tx = w4.x + SCALING * dx;
        float ty = w4.y + SCALING * dy;
        float tz = w4.z + SCALING * dz;
        float tw = w4.w + SCALING * dw;
        acc += tx * tx + ty * ty + tz * tz + tw * tw;
    }
#pragma unroll
    for (int off = 32; off > 0; off >>= 1)
        acc += __shfl_down(acc, off, 64);

    if (lane == 0) {
        float ms = mag[o] / (sqrtf(acc) + EPS_N);
        mag_scale[o] = ms;
#pragma unroll
        for (int r = 0; r < RANK; ++r)
            Bm[o * RANK + r] = SCALING * b[r] * ms;
    }
}

// ---------------------------------------------------------------------------
// Pass 2: lx[m][r] = sum_i x[m][i] * A[r][i].
// Block = 4 waves; wave w handles row m = blockIdx.x*4 + w.
// ---------------------------------------------------------------------------
__global__ __launch_bounds__(256) void k_lorax(
    const float* __restrict__ x,   // [M_ROWS, D_IN]
    const float* __restrict__ A,   // [RANK, D_IN]
    float* __restrict__ lx)        // [M_ROWS, RANK]
{
    const int wave = threadIdx.x >> 6;
    const int lane = threadIdx.x & 63;
    const int m = blockIdx.x * 4 + wave;
    const float* xrow = x + (size_t)m * D_IN;

    float acc[RANK] = {};
    for (int i = lane * 4; i < D_IN; i += 64 * 4) {
        float4 x4 = *(const float4*)(xrow + i);
#pragma unroll
        for (int r = 0; r < RANK; ++r) {
            float4 a4 = *(const float4*)(A + r * D_IN + i);
            acc[r] += x4.x * a4.x + x4.y * a4.y + x4.z * a4.z + x4.w * a4.w;
        }
    }
#pragma unroll
    for (int r = 0; r < RANK; ++r) {
#pragma unroll
        for (int off = 32; off > 0; off >>= 1)
            acc[r] += __shfl_down(acc[r], off, 64);
    }
    if (lane == 0) {
#pragma unroll
        for (int r = 0; r < RANK; ++r)
            lx[m * RANK + r] = acc[r];
    }
}

// ---------------------------------------------------------------------------
// Pass 3: out[m][o] = base[m][o]*ms[o] + sum_r lx[m][r]*Bm[o][r].
// Tile: o-tile = 1024 (one float4 column per thread), m-tile = 16.
// Bm/ms for a thread's 4 o's live in registers; lx tile staged in LDS.
// ---------------------------------------------------------------------------
#define MT 16
#define OT 1024

__global__ __launch_bounds__(256) void k_out(
    const float* __restrict__ base,       // [M_ROWS, D_OUT]
    const float* __restrict__ lx,         // [M_ROWS, RANK]
    const float* __restrict__ Bm,         // [D_OUT, RANK]
    const float* __restrict__ mag_scale,  // [D_OUT]
    float* __restrict__ out)              // [M_ROWS, D_OUT]
{
    const int ob = (blockIdx.x & (D_OUT / OT - 1)) * OT;   // 4 o-tiles
    const int mb = (blockIdx.x / (D_OUT / OT)) * MT;
    const int o = ob + threadIdx.x * 4;

    float ms[4];
    float bm[4][RANK];
#pragma unroll
    for (int j = 0; j < 4; ++j) {
        ms[j] = mag_scale[o + j];
#pragma unroll
        for (int r = 0; r < RANK; ++r)
            bm[j][r] = Bm[(size_t)(o + j) * RANK + r];
    }

    __shared__ float slx[MT][RANK];
    if (threadIdx.x < MT * RANK) {
        int mi = threadIdx.x / RANK, r = threadIdx.x % RANK;
        slx[mi][r] = lx[(size_t)(mb + mi) * RANK + r];
    }
    __syncthreads();

    for (int mi = 0; mi < MT; ++mi) {
        const size_t row = (size_t)(mb + mi) * D_OUT + o;
        float4 b4 = *(const float4*)(base + row);
        float l[RANK];
#pragma unroll
        for (int r = 0; r < RANK; ++r) l[r] = slx[mi][r];

        float rx = b4.x * ms[0];
        float ry = b4.y * ms[1];
        float rz = b4.z * ms[2];
        float rw = b4.w * ms[3];
#pragma unroll
        for (int r = 0; r < RANK; ++r) {
            rx += l[r] * bm[0][r];
            ry += l[r] * bm[1][r];
            rz += l[r] * bm[2][r];
            rw += l[r] * bm[3][r];
        }
        float4 o4 = make_float4(rx, ry, rz, rw);
        *(float4*)(out + row) = o4;
    }
}

// ---------------------------------------------------------------------------
extern "C" void kernel_launch(void* const* d_in, const int* in_sizes, int n_in,
                              void* d_out, int out_size, void* d_ws, size_t ws_size,
                              hipStream_t stream) {
    const float* x        = (const float*)d_in[0];  // [4,2048,4096]
    const float* base_out = (const float*)d_in[1];  // [4,2048,4096]
    const float* base_w   = (const float*)d_in[2];  // [4096,4096]
    const float* lora_A   = (const float*)d_in[3];  // [8,4096]
    const float* lora_B   = (const float*)d_in[4];  // [4096,8]
    const float* mag      = (const float*)d_in[5];  // [4096]
    float* out = (float*)d_out;

    // workspace layout
    float* mag_scale = (float*)d_ws;                         // 4096 f
    float* Bm        = mag_scale + D_OUT;                    // 4096*8 f
    float* lx        = Bm + (size_t)D_OUT * RANK;            // 8192*8 f

    k_magscale<<<D_OUT / 4, 256, 0, stream>>>(base_w, lora_A, lora_B, mag,
                                              mag_scale, Bm);
    k_lorax<<<M_ROWS / 4, 256, 0, stream>>>(x, lora_A, lx);
    k_out<<<(M_ROWS / MT) * (D_OUT / OT), 256, 0, stream>>>(base_out, lx, Bm,
                                                            mag_scale, out);
}

// Round 2
// 414.991 us; speedup vs baseline: 1.0581x; 1.0581x over previous
//
#include <hip/hip_runtime.h>
#include <math.h>

#define D_IN   4096
#define D_OUT  4096
#define M_ROWS 8192          // B*S = 4*2048
#define RANK   8
#define SCALING 2.0f
#define EPS_N  1e-8f

// ---------------------------------------------------------------------------
// Pass 1: mag_scale[o] = mag[o] / (||W_o + 2*B_o*A|| + eps)
//         Bm[o][r]     = 2 * B[o][r] * mag_scale[o]
// G=2 rows per wave to amortize the 8 A-row loads. 4 waves/block, 8 rows/block,
// 512 blocks -> 2 blocks/CU -> 8 waves/CU for latency hiding.
// ---------------------------------------------------------------------------
__global__ __launch_bounds__(256, 2) void k_magscale(
    const float* __restrict__ W,     // [D_OUT, D_IN]
    const float* __restrict__ A,     // [RANK, D_IN]
    const float* __restrict__ Bl,    // [D_OUT, RANK]
    const float* __restrict__ mag,   // [D_OUT]
    float* __restrict__ mag_scale,   // [D_OUT]
    float* __restrict__ Bm)          // [D_OUT, RANK]
{
    const int wave = threadIdx.x >> 6;
    const int lane = threadIdx.x & 63;
    const int o0 = blockIdx.x * 8 + wave * 2;       // rows o0, o0+1
    const float* W0 = W + (size_t)o0 * D_IN;
    const float* W1 = W0 + D_IN;

    float b0[RANK], b1[RANK];
#pragma unroll
    for (int r = 0; r < RANK; ++r) {
        b0[r] = Bl[o0 * RANK + r];
        b1[r] = Bl[(o0 + 1) * RANK + r];
    }

    float acc0 = 0.f, acc1 = 0.f;
    for (int i = lane * 4; i < D_IN; i += 256) {
        float4 a4[RANK];
#pragma unroll
        for (int r = 0; r < RANK; ++r)
            a4[r] = *(const float4*)(A + r * D_IN + i);
        float4 w0 = *(const float4*)(W0 + i);
        float4 w1 = *(const float4*)(W1 + i);

        float d0x = 0.f, d0y = 0.f, d0z = 0.f, d0w = 0.f;
        float d1x = 0.f, d1y = 0.f, d1z = 0.f, d1w = 0.f;
#pragma unroll
        for (int r = 0; r < RANK; ++r) {
            d0x += b0[r] * a4[r].x; d0y += b0[r] * a4[r].y;
            d0z += b0[r] * a4[r].z; d0w += b0[r] * a4[r].w;
            d1x += b1[r] * a4[r].x; d1y += b1[r] * a4[r].y;
            d1z += b1[r] * a4[r].z; d1w += b1[r] * a4[r].w;
        }
        float t;
        t = w0.x + SCALING * d0x; acc0 += t * t;
        t = w0.y + SCALING * d0y; acc0 += t * t;
        t = w0.z + SCALING * d0z; acc0 += t * t;
        t = w0.w + SCALING * d0w; acc0 += t * t;
        t = w1.x + SCALING * d1x; acc1 += t * t;
        t = w1.y + SCALING * d1y; acc1 += t * t;
        t = w1.z + SCALING * d1z; acc1 += t * t;
        t = w1.w + SCALING * d1w; acc1 += t * t;
    }
#pragma unroll
    for (int off = 32; off > 0; off >>= 1) {
        acc0 += __shfl_down(acc0, off, 64);
        acc1 += __shfl_down(acc1, off, 64);
    }
    if (lane == 0) {
        float ms0 = mag[o0] / (sqrtf(acc0) + EPS_N);
        float ms1 = mag[o0 + 1] / (sqrtf(acc1) + EPS_N);
        mag_scale[o0] = ms0;
        mag_scale[o0 + 1] = ms1;
#pragma unroll
        for (int r = 0; r < RANK; ++r) {
            Bm[o0 * RANK + r]       = SCALING * b0[r] * ms0;
            Bm[(o0 + 1) * RANK + r] = SCALING * b1[r] * ms1;
        }
    }
}

// ---------------------------------------------------------------------------
// Fused pass 2+3. Block = 16 m-rows (4 waves x G=4 rows).
// Phase A: lx[16][8] = x-tile . A^T  (A fragment amortized over 4 rows),
//          result kept in LDS.
// Phase B: out[m][o] = base[m][o]*ms[o] + sum_r lx[m][r]*Bm[o][r],
//          o-tile = 1024 (float4/thread), 4 tiles.
// 512 blocks -> 2 blocks/CU -> 8 waves/CU.
// ---------------------------------------------------------------------------
#define MT 16

__global__ __launch_bounds__(256, 2) void k_fused(
    const float* __restrict__ x,          // [M_ROWS, D_IN]
    const float* __restrict__ A,          // [RANK, D_IN]
    const float* __restrict__ base,       // [M_ROWS, D_OUT]
    const float* __restrict__ Bm,         // [D_OUT, RANK]
    const float* __restrict__ mag_scale,  // [D_OUT]
    float* __restrict__ out)              // [M_ROWS, D_OUT]
{
    const int wave = threadIdx.x >> 6;
    const int lane = threadIdx.x & 63;
    const int mb = blockIdx.x * MT;

    __shared__ float slx[MT][RANK];

    // ---------------- Phase A: lx for rows mb + wave*4 + {0..3} ------------
    const float* x0 = x + (size_t)(mb + wave * 4) * D_IN;
    float acc[4][RANK];
#pragma unroll
    for (int g = 0; g < 4; ++g)
#pragma unroll
        for (int r = 0; r < RANK; ++r) acc[g][r] = 0.f;

    for (int i = lane * 4; i < D_IN; i += 256) {
        float4 a4[RANK];
#pragma unroll
        for (int r = 0; r < RANK; ++r)
            a4[r] = *(const float4*)(A + r * D_IN + i);
#pragma unroll
        for (int g = 0; g < 4; ++g) {
            float4 x4 = *(const float4*)(x0 + (size_t)g * D_IN + i);
#pragma unroll
            for (int r = 0; r < RANK; ++r)
                acc[g][r] += x4.x * a4[r].x + x4.y * a4[r].y +
                             x4.z * a4[r].z + x4.w * a4[r].w;
        }
    }
#pragma unroll
    for (int g = 0; g < 4; ++g) {
#pragma unroll
        for (int r = 0; r < RANK; ++r) {
            float v = acc[g][r];
#pragma unroll
            for (int off = 32; off > 0; off >>= 1)
                v += __shfl_down(v, off, 64);
            if (lane == 0) slx[wave * 4 + g][r] = v;
        }
    }
    __syncthreads();

    // ---------------- Phase B: epilogue over full D_OUT --------------------
#pragma unroll
    for (int tile = 0; tile < 4; ++tile) {
        const int o = tile * 1024 + threadIdx.x * 4;
        const float4 ms4 = *(const float4*)(mag_scale + o);
        float bm[4][RANK];
#pragma unroll
        for (int j = 0; j < 4; ++j) {
            float4 lo = *(const float4*)(Bm + (size_t)(o + j) * RANK);
            float4 hi = *(const float4*)(Bm + (size_t)(o + j) * RANK + 4);
            bm[j][0] = lo.x; bm[j][1] = lo.y; bm[j][2] = lo.z; bm[j][3] = lo.w;
            bm[j][4] = hi.x; bm[j][5] = hi.y; bm[j][6] = hi.z; bm[j][7] = hi.w;
        }
        for (int mi = 0; mi < MT; ++mi) {
            const size_t row = (size_t)(mb + mi) * D_OUT + o;
            float4 b4 = *(const float4*)(base + row);
            float l[RANK];
#pragma unroll
            for (int r = 0; r < RANK; ++r) l[r] = slx[mi][r];

            float rx = b4.x * ms4.x;
            float ry = b4.y * ms4.y;
            float rz = b4.z * ms4.z;
            float rw = b4.w * ms4.w;
#pragma unroll
            for (int r = 0; r < RANK; ++r) {
                rx += l[r] * bm[0][r];
                ry += l[r] * bm[1][r];
                rz += l[r] * bm[2][r];
                rw += l[r] * bm[3][r];
            }
            *(float4*)(out + row) = make_float4(rx, ry, rz, rw);
        }
    }
}

// ---------------------------------------------------------------------------
extern "C" void kernel_launch(void* const* d_in, const int* in_sizes, int n_in,
                              void* d_out, int out_size, void* d_ws, size_t ws_size,
                              hipStream_t stream) {
    const float* x        = (const float*)d_in[0];  // [4,2048,4096]
    const float* base_out = (const float*)d_in[1];  // [4,2048,4096]
    const float* base_w   = (const float*)d_in[2];  // [4096,4096]
    const float* lora_A   = (const float*)d_in[3];  // [8,4096]
    const float* lora_B   = (const float*)d_in[4];  // [4096,8]
    const float* mag      = (const float*)d_in[5];  // [4096]
    float* out = (float*)d_out;

    float* mag_scale = (float*)d_ws;                // 4096 f
    float* Bm        = mag_scale + D_OUT;           // 4096*8 f

    k_magscale<<<D_OUT / 8, 256, 0, stream>>>(base_w, lora_A, lora_B, mag,
                                              mag_scale, Bm);
    k_fused<<<M_ROWS / MT, 256, 0, stream>>>(x, lora_A, base_out, Bm,
                                             mag_scale, out);
}